// Round 3
// baseline (889.472 us; speedup 1.0000x reference)
//
#include <hip/hip_runtime.h>

// Problem: S=512, B=256, I=64, H=512, O=25.
// y depends only on batch row 255 -> compute only that row's recurrence.
//
// rnn_pre : xi[t][h] = x[t,255,:].W_ih[h,:] + b_ih[h] + b_hh[h]; re-inits the
//           exchange buffers (sign=1 = not-ready) every launch.
// rnn_seq : 512 sequential steps h = relu(xi_t + W_hh h_prev) on 64 blocks of
//           ONE WAVE each (8 rows/block, W_hh register-resident, h register-
//           resident). NO LDS and NO barriers in the step loop: lane l's
//           polled 8-word chunk IS its FMA k-chunk, and the row sums are
//           formed by a wave-synchronous reduce-scatter shuffle tree.
//           Cross-block exchange: PROVEN protocol from the 787us kernel,
//           unchanged -- 32-bit words, generation in the SIGN BIT (relu =>
//           h >= 0), double-buffered by s&1, phase=(s>>1)&1; the progress
//           invariant bounds inter-block skew to <2 steps, which the encoding
//           exactly disambiguates. Relaxed agent-scope atomics only.
// rnn_post: y[t] = h_t . W2^T + b2 (512x25).
//
// Workspace: xh[512*512] (xi, progressively overwritten by hseq -- each block
// writes h only over its OWN already-consumed xi rows; strictly ordered),
// hg[2*512] exchange words.

#define S_ 512
#define B_ 256
#define I_ 64
#define H_ 512
#define O_ 25
#define NB_ 64  // single-wave worker blocks
#define RW_ 8   // rows per block (H_/NB_)

__global__ __launch_bounds__(256) void rnn_pre(
    const float* __restrict__ x, const float* __restrict__ W_ih,
    const float* __restrict__ b_ih, const float* __restrict__ b_hh,
    float* __restrict__ xh, unsigned* __restrict__ hg) {
  const int t = blockIdx.x;
  const int tid = threadIdx.x;
  const int o = blockIdx.y * 256 + tid;
  if (t == 0 && blockIdx.y == 0) {
    // re-init every launch: no reliance on workspace poison / prior state.
    hg[tid] = 0x80000000u;
    hg[tid + 256] = 0x80000000u;
    hg[tid + 512] = 0x80000000u;
    hg[tid + 768] = 0x80000000u;
  }
  __shared__ float xr[I_];
  if (tid < I_) xr[tid] = x[(t * B_ + (B_ - 1)) * I_ + tid];
  __syncthreads();
  float acc = b_ih[o] + b_hh[o];
  const float4* wp = (const float4*)(W_ih + o * I_);
#pragma unroll
  for (int j = 0; j < I_ / 4; ++j) {
    float4 w4 = wp[j];
    acc += w4.x * xr[4 * j] + w4.y * xr[4 * j + 1] + w4.z * xr[4 * j + 2] +
           w4.w * xr[4 * j + 3];
  }
  xh[t * H_ + o] = acc;
}

__global__ __launch_bounds__(64) void rnn_seq(
    const float* __restrict__ W_hh, float* __restrict__ xh,
    unsigned* hg) {
  const int l = threadIdx.x;   // 0..63
  const int b = blockIdx.x;    // 0..63
  const int own_lo = b * RW_;  // this block's 8 rows
  const int k0 = l * RW_;      // this lane's 8-wide k-chunk (== its poll chunk)

  // Weights register-resident: w[r][j] = W_hh[own_lo+r][k0+j].
  float w[RW_][RW_];
#pragma unroll
  for (int r = 0; r < RW_; ++r) {
    const float4* wp = (const float4*)(W_hh + (own_lo + r) * H_ + k0);
    float4 wa = wp[0], wb = wp[1];
    w[r][0] = wa.x; w[r][1] = wa.y; w[r][2] = wa.z; w[r][3] = wa.w;
    w[r][4] = wb.x; w[r][5] = wb.y; w[r][6] = wb.z; w[r][7] = wb.w;
  }

  // h_{-1} = 0, register-resident (lane's own k-chunk).
  float h[RW_];
#pragma unroll
  for (int j = 0; j < RW_; ++j) h[j] = 0.0f;

  // xi for step 0 (lanes 0..7 hold the block's 8 rows).
  float xiv = (l < RW_) ? xh[own_lo + l] : 0.0f;

  const unsigned long long sm = 0x8000000080000000ull;

  for (int s = 0; s < S_; ++s) {
    // ---- matvec partials: acc[r] = sum_j w[r][j] * h[j]  (8 ILP chains) ----
    float acc[RW_];
#pragma unroll
    for (int r = 0; r < RW_; ++r) {
      float a = w[r][0] * h[0];
      a = fmaf(w[r][1], h[1], a);
      a = fmaf(w[r][2], h[2], a);
      a = fmaf(w[r][3], h[3], a);
      a = fmaf(w[r][4], h[4], a);
      a = fmaf(w[r][5], h[5], a);
      a = fmaf(w[r][6], h[6], a);
      a = fmaf(w[r][7], h[7], a);
      acc[r] = a;
    }

    // ---- reduce-scatter across the wave: lane l ends with row (l&7) ----
    float s4[4];
#pragma unroll
    for (int i = 0; i < 4; ++i) {
      float e = acc[2 * i] + __shfl_xor(acc[2 * i], 1);
      float o2 = acc[2 * i + 1] + __shfl_xor(acc[2 * i + 1], 1);
      s4[i] = (l & 1) ? o2 : e;
    }
    float s2[2];
#pragma unroll
    for (int i = 0; i < 2; ++i) {
      float e = s4[2 * i] + __shfl_xor(s4[2 * i], 2);
      float o2 = s4[2 * i + 1] + __shfl_xor(s4[2 * i + 1], 2);
      s2[i] = (l & 2) ? o2 : e;
    }
    float e = s2[0] + __shfl_xor(s2[0], 4);
    float o2 = s2[1] + __shfl_xor(s2[1], 4);
    float v = (l & 4) ? o2 : e;
    v += __shfl_xor(v, 8);
    v += __shfl_xor(v, 16);
    v += __shfl_xor(v, 32);
    // lane l (l<8): v = full dot of row own_lo+l over all 512 k.

    const unsigned phase = (unsigned)((s >> 1) & 1);
    unsigned* buf = hg + (s & 1) * H_;

    if (l < RW_) {
      float hv = fmaxf(v + xiv, 0.0f);
      xh[s * H_ + own_lo + l] = hv;  // hseq (over this block's consumed xi)
      __hip_atomic_store(buf + own_lo + l,
                         __float_as_uint(hv) | (phase << 31),
                         __ATOMIC_RELAXED, __HIP_MEMORY_SCOPE_AGENT);
    }

    if (s == S_ - 1) break;  // no poll needed after last step

    // prefetch next step's xi (hidden under the poll RTT)
    if (l < RW_) xiv = xh[(s + 1) * H_ + own_lo + l];

    // ---- poll this lane's 8 words (4x u64), sign==phase on all 8 ----
    const unsigned long long ph64 = phase ? sm : 0ull;
    const unsigned long long* ap = (const unsigned long long*)(buf + k0);
    unsigned long long p0, p1, p2, p3;
    for (;;) {
      p0 = __hip_atomic_load(ap + 0, __ATOMIC_RELAXED, __HIP_MEMORY_SCOPE_AGENT);
      p1 = __hip_atomic_load(ap + 1, __ATOMIC_RELAXED, __HIP_MEMORY_SCOPE_AGENT);
      p2 = __hip_atomic_load(ap + 2, __ATOMIC_RELAXED, __HIP_MEMORY_SCOPE_AGENT);
      p3 = __hip_atomic_load(ap + 3, __ATOMIC_RELAXED, __HIP_MEMORY_SCOPE_AGENT);
      unsigned long long t = (p0 ^ ph64) | (p1 ^ ph64) | (p2 ^ ph64) | (p3 ^ ph64);
      if ((t & sm) == 0ull) break;
    }
    h[0] = __uint_as_float((unsigned)p0 & 0x7fffffffu);
    h[1] = __uint_as_float((unsigned)(p0 >> 32) & 0x7fffffffu);
    h[2] = __uint_as_float((unsigned)p1 & 0x7fffffffu);
    h[3] = __uint_as_float((unsigned)(p1 >> 32) & 0x7fffffffu);
    h[4] = __uint_as_float((unsigned)p2 & 0x7fffffffu);
    h[5] = __uint_as_float((unsigned)(p2 >> 32) & 0x7fffffffu);
    h[6] = __uint_as_float((unsigned)p3 & 0x7fffffffu);
    h[7] = __uint_as_float((unsigned)(p3 >> 32) & 0x7fffffffu);
  }
}

__global__ __launch_bounds__(256) void rnn_post(
    const float* __restrict__ hseq, const float* __restrict__ W2,
    const float* __restrict__ b2, float* __restrict__ y) {
  const int t = blockIdx.x;
  const int tid = threadIdx.x;
  __shared__ float hl[H_];
  __shared__ float part[256];
  for (int n = tid; n < H_; n += 256) hl[n] = hseq[t * H_ + n];
  __syncthreads();
  const int o = tid >> 3;
  const int seg = tid & 7;
  float acc = 0.0f;
  if (o < O_) {
    const float4* wp = (const float4*)(W2 + o * H_ + seg * 64);
    const float4* hp = (const float4*)(hl + seg * 64);
#pragma unroll
    for (int j = 0; j < 16; ++j) {
      float4 w4 = wp[j];
      float4 h4 = hp[j];
      acc += w4.x * h4.x + w4.y * h4.y + w4.z * h4.z + w4.w * h4.w;
    }
  }
  part[tid] = acc;
  __syncthreads();
  if (tid < O_) {
    float sum = 0.0f;
#pragma unroll
    for (int j = 0; j < 8; ++j) sum += part[tid * 8 + j];
    y[t * O_ + tid] = sum + b2[tid];
  }
}

extern "C" void kernel_launch(void* const* d_in, const int* in_sizes, int n_in,
                              void* d_out, int out_size, void* d_ws, size_t ws_size,
                              hipStream_t stream) {
  const float* x    = (const float*)d_in[0];
  const float* W_ih = (const float*)d_in[1];
  const float* W_hh = (const float*)d_in[2];
  const float* b_ih = (const float*)d_in[3];
  const float* b_hh = (const float*)d_in[4];
  const float* W2   = (const float*)d_in[5];
  const float* b2   = (const float*)d_in[6];
  float* y = (float*)d_out;

  float* xh = (float*)d_ws;                  // [512*512] xi -> hseq (aliased)
  unsigned* hg = (unsigned*)(xh + S_ * H_);  // [2*512] sign-tagged exchange

  rnn_pre<<<dim3(S_, 2), 256, 0, stream>>>(x, W_ih, b_ih, b_hh, xh, hg);
  rnn_seq<<<NB_, 64, 0, stream>>>(W_hh, xh, hg);
  rnn_post<<<S_, 256, 0, stream>>>(xh, W2, b2, y);
}

// Round 4
// 874.986 us; speedup vs baseline: 1.0166x; 1.0166x over previous
//
#include <hip/hip_runtime.h>

// Problem: S=512, B=256, I=64, H=512, O=25.
// y depends only on batch row 255 -> compute only that row's recurrence.
//
// rnn_pre : xi[t][h] = x[t,255,:].W_ih[h,:] + b_ih[h] + b_hh[h]; re-inits the
//           exchange buffers (sign=1 = not-ready) every launch.
// rnn_seq : 512 sequential steps h = relu(xi_t + W_hh h_prev) on 8 blocks x
//           512 threads (64 rows/block, W_hh register-resident, 64 f/thread).
//           Cross-block exchange: PROVEN protocol (787us kernel) -- 32-bit
//           words, generation in the SIGN BIT (relu => h>=0), double-buffered
//           by s&1, phase=(s>>1)&1; progress invariant bounds skew <2 steps.
//           Relaxed agent-scope atomics only. Changes vs the 700us rnn_seq:
//           8 producers instead of 16 (fewer coherence domains + less skew),
//           u64 tagged stores (2 words/transaction), poll-all with 2-deep
//           software-pipelined u64 polls (detection ~0.75 RTT, not ~1.5 RTT).
// rnn_post: y[t] = h_t . W2^T + b2 (512x25).
//
// Workspace: xh[512*512] (xi, progressively overwritten by hseq -- each block
// writes h only over its OWN already-consumed xi rows; strictly ordered),
// hg[2*512] exchange words.

#define S_ 512
#define B_ 256
#define I_ 64
#define H_ 512
#define O_ 25
#define NB_ 8   // worker blocks in rnn_seq
#define RB_ 64  // rows per block (H_/NB_)

__global__ __launch_bounds__(256) void rnn_pre(
    const float* __restrict__ x, const float* __restrict__ W_ih,
    const float* __restrict__ b_ih, const float* __restrict__ b_hh,
    float* __restrict__ xh, unsigned* __restrict__ hg) {
  const int t = blockIdx.x;
  const int tid = threadIdx.x;
  const int o = blockIdx.y * 256 + tid;
  if (t == 0 && blockIdx.y == 0) {
    // re-init every launch: no reliance on workspace poison / prior state.
    hg[tid] = 0x80000000u;
    hg[tid + 256] = 0x80000000u;
    hg[tid + 512] = 0x80000000u;
    hg[tid + 768] = 0x80000000u;
  }
  __shared__ float xr[I_];
  if (tid < I_) xr[tid] = x[(t * B_ + (B_ - 1)) * I_ + tid];
  __syncthreads();
  float acc = b_ih[o] + b_hh[o];
  const float4* wp = (const float4*)(W_ih + o * I_);
#pragma unroll
  for (int j = 0; j < I_ / 4; ++j) {
    float4 w4 = wp[j];
    acc += w4.x * xr[4 * j] + w4.y * xr[4 * j + 1] + w4.z * xr[4 * j + 2] +
           w4.w * xr[4 * j + 3];
  }
  xh[t * H_ + o] = acc;
}

__global__ __launch_bounds__(512) void rnn_seq(
    const float* __restrict__ W_hh, float* __restrict__ xh,
    unsigned* hg) {
  const int tid = threadIdx.x;   // 0..511
  const int b = blockIdx.x;      // 0..7
  const int r = tid & 63;        // row within block's 64 rows
  const int seg = tid >> 6;      // 0..7 : 64-wide k-chunk (== wave id)
  const int row = b * RB_ + r;
  const int k0 = seg * 64;
  const int own_lo = b * RB_;
  const int lane = tid & 63;

  __shared__ __align__(16) float h_l[H_];
  __shared__ __align__(16) float part[8 * 64];  // seg-major [seg][row]

  // W_hh register-resident: thread (r,seg) holds W_hh[row][k0..k0+63].
  float w[64];
  {
    const float4* wp = (const float4*)(W_hh + row * H_ + k0);
#pragma unroll
    for (int j = 0; j < 16; ++j) {
      float4 v = wp[j];
      w[4 * j] = v.x; w[4 * j + 1] = v.y;
      w[4 * j + 2] = v.z; w[4 * j + 3] = v.w;
    }
  }
  for (int n = tid; n < H_; n += 512) h_l[n] = 0.0f;  // h_{-1} = 0

  // finalizers: wave 0 lanes 0..31, rows 2j,2j+1; xi as float2.
  const bool fin = (tid < 32);
  float2 xiv = make_float2(0.f, 0.f);
  if (fin) xiv = *(const float2*)(xh + own_lo + 2 * tid);

  // pollers: tid in [128,384) -> word pair 2p,2p+1 (p = tid-128), all 512
  // words (incl. own block's -- they pass once our own stores land; no
  // deadlock: producers store unconditionally before waiting).
  const bool pol = (tid >= 128) && (tid < 384);
  const int p = tid - 128;

  const unsigned long long sm = 0x8000000080000000ull;
  __syncthreads();

  for (int s = 0; s < S_; ++s) {
    // ---- partial dot, 4 independent accumulator chains ----
    float a0 = 0.f, a1 = 0.f, a2 = 0.f, a3 = 0.f;
    const float4* hp = (const float4*)(h_l + k0);  // broadcast reads
#pragma unroll
    for (int j = 0; j < 16; ++j) {
      float4 hv = hp[j];
      a0 = fmaf(w[4 * j + 0], hv.x, a0);
      a1 = fmaf(w[4 * j + 1], hv.y, a1);
      a2 = fmaf(w[4 * j + 2], hv.z, a2);
      a3 = fmaf(w[4 * j + 3], hv.w, a3);
    }
    part[seg * 64 + r] = (a0 + a1) + (a2 + a3);
    __syncthreads();  // barrier A: partials complete

    const unsigned phase = (unsigned)((s >> 1) & 1);
    unsigned* buf = hg + (s & 1) * H_;

    if (fin) {
      const int j = tid;  // 0..31, rows 2j and 2j+1
      const float2* pp = (const float2*)part;  // index s*32 + j
      float sx = xiv.x, sy = xiv.y;
#pragma unroll
      for (int q = 0; q < 8; ++q) {
        float2 f = pp[q * 32 + j];
        sx += f.x;
        sy += f.y;
      }
      float h0 = fmaxf(sx, 0.0f);
      float h1 = fmaxf(sy, 0.0f);
      *(float2*)(xh + s * H_ + own_lo + 2 * j) = make_float2(h0, h1);  // hseq
      unsigned long long uv =
          (unsigned long long)(__float_as_uint(h0) | (phase << 31)) |
          ((unsigned long long)(__float_as_uint(h1) | (phase << 31)) << 32);
      __hip_atomic_store((unsigned long long*)(buf + own_lo + 2 * j), uv,
                         __ATOMIC_RELAXED, __HIP_MEMORY_SCOPE_AGENT);
    }

    if (s == S_ - 1) break;  // no poll needed after last step

    // prefetch next step's xi (hidden under the poll RTT)
    if (fin) xiv = *(const float2*)(xh + (s + 1) * H_ + own_lo + 2 * tid);

    if (pol) {
      const unsigned long long ph64 = phase ? sm : 0ull;
      const unsigned long long* ap =
          (const unsigned long long*)buf + p;
      // 2-deep software-pipelined poll: next load in flight while testing
      // the previous one -> detection granularity ~RTT/2.
      unsigned long long va = __hip_atomic_load(ap, __ATOMIC_RELAXED,
                                                __HIP_MEMORY_SCOPE_AGENT);
      unsigned long long vb = __hip_atomic_load(ap, __ATOMIC_RELAXED,
                                                __HIP_MEMORY_SCOPE_AGENT);
      for (;;) {
        if (((va ^ ph64) & sm) == 0ull) break;
        va = vb;
        vb = __hip_atomic_load(ap, __ATOMIC_RELAXED,
                               __HIP_MEMORY_SCOPE_AGENT);
      }
      float2 hv;
      hv.x = __uint_as_float((unsigned)va & 0x7fffffffu);
      hv.y = __uint_as_float((unsigned)(va >> 32) & 0x7fffffffu);
      *(float2*)(h_l + 2 * p) = hv;
    }
    __syncthreads();  // barrier B: h_l complete
  }
}

__global__ __launch_bounds__(256) void rnn_post(
    const float* __restrict__ hseq, const float* __restrict__ W2,
    const float* __restrict__ b2, float* __restrict__ y) {
  const int t = blockIdx.x;
  const int tid = threadIdx.x;
  __shared__ float hl[H_];
  __shared__ float part[256];
  for (int n = tid; n < H_; n += 256) hl[n] = hseq[t * H_ + n];
  __syncthreads();
  const int o = tid >> 3;
  const int seg = tid & 7;
  float acc = 0.0f;
  if (o < O_) {
    const float4* wp = (const float4*)(W2 + o * H_ + seg * 64);
    const float4* hp = (const float4*)(hl + seg * 64);
#pragma unroll
    for (int j = 0; j < 16; ++j) {
      float4 w4 = wp[j];
      float4 h4 = hp[j];
      acc += w4.x * h4.x + w4.y * h4.y + w4.z * h4.z + w4.w * h4.w;
    }
  }
  part[tid] = acc;
  __syncthreads();
  if (tid < O_) {
    float sum = 0.0f;
#pragma unroll
    for (int j = 0; j < 8; ++j) sum += part[tid * 8 + j];
    y[t * O_ + tid] = sum + b2[tid];
  }
}

extern "C" void kernel_launch(void* const* d_in, const int* in_sizes, int n_in,
                              void* d_out, int out_size, void* d_ws, size_t ws_size,
                              hipStream_t stream) {
  const float* x    = (const float*)d_in[0];
  const float* W_ih = (const float*)d_in[1];
  const float* W_hh = (const float*)d_in[2];
  const float* b_ih = (const float*)d_in[3];
  const float* b_hh = (const float*)d_in[4];
  const float* W2   = (const float*)d_in[5];
  const float* b2   = (const float*)d_in[6];
  float* y = (float*)d_out;

  float* xh = (float*)d_ws;                  // [512*512] xi -> hseq (aliased)
  unsigned* hg = (unsigned*)(xh + S_ * H_);  // [2*512] sign-tagged exchange

  rnn_pre<<<dim3(S_, 2), 256, 0, stream>>>(x, W_ih, b_ih, b_hh, xh, hg);
  rnn_seq<<<NB_, 512, 0, stream>>>(W_hh, xh, hg);
  rnn_post<<<S_, 256, 0, stream>>>(xh, W2, b2, y);
}

// Round 5
// 753.324 us; speedup vs baseline: 1.1807x; 1.1615x over previous
//
#include <hip/hip_runtime.h>

// Problem: S=512, B=256, I=64, H=512, O=25.
// y depends only on batch row 255 -> compute only that row's recurrence.
//
// rnn_pre : xi[t][h] = x[t,255,:].W_ih[h,:] + b_ih[h] + b_hh[h]; re-inits the
//           exchange buffers (sign=1 = not-ready) every launch.
// rnn_seq : 512 sequential steps h = relu(xi_t + W_hh h_prev) on 16 blocks x
//           256 threads (32 rows/block, W_hh register-resident). Cross-block
//           exchange: PROVEN protocol -- 32-bit words, generation in the SIGN
//           BIT (relu => h>=0), double-buffered by s&1, phase=(s>>1)&1;
//           data-dependency invariant bounds skew <2 steps (independent of
//           barrier flavor). Relaxed agent-scope atomics only.
//           Round-5 changes (mechanism-targeted, protocol unchanged):
//           (1) lgkm-only raw barriers: __syncthreads drains vmcnt(0), which
//               serialized every step on the finalizers' store-acks to the
//               coherence point; only LDS visibility is actually required.
//           (2) adaptive poll phase-alignment: per-lane delay D (s_sleep
//               units) before the first poll, adapted on poll-iteration
//               count, so the first sample lands just after visibility
//               (kills the ~RTT quantization tail). Perf-only: worst case
//               equals baseline polling; termination unaffected.
//           (3) u64 pair-polls; transposed part[] + ds_read_b128 finalize.
// rnn_post: y[t] = h_t . W2^T + b2 (512x25).
//
// Workspace: xh[512*512] (xi, progressively overwritten by hseq -- each block
// writes h only over its OWN already-consumed xi rows; strictly ordered),
// hg[2*512] exchange words.

#define S_ 512
#define B_ 256
#define I_ 64
#define H_ 512
#define O_ 25
#define G_ 16   // blocks in rnn_seq
#define R_ 32   // rows per block (H_/G_)

// Barrier with LDS-only drain: no vmcnt(0) -> store-acks/prefetch loads stay
// in flight across it. sched_barrier(0) fences compiler motion (rule #18).
static __device__ __forceinline__ void wg_barrier_lds() {
  __builtin_amdgcn_sched_barrier(0);
  asm volatile("s_waitcnt lgkmcnt(0)" ::: "memory");
  __builtin_amdgcn_s_barrier();
  __builtin_amdgcn_sched_barrier(0);
}

__global__ __launch_bounds__(256) void rnn_pre(
    const float* __restrict__ x, const float* __restrict__ W_ih,
    const float* __restrict__ b_ih, const float* __restrict__ b_hh,
    float* __restrict__ xh, unsigned* __restrict__ hg) {
  const int t = blockIdx.x;
  const int tid = threadIdx.x;
  const int o = blockIdx.y * 256 + tid;
  if (t == 0 && blockIdx.y == 0) {
    // re-init every launch: no reliance on workspace poison / prior state.
    hg[tid] = 0x80000000u;
    hg[tid + 256] = 0x80000000u;
    hg[tid + 512] = 0x80000000u;
    hg[tid + 768] = 0x80000000u;
  }
  __shared__ float xr[I_];
  if (tid < I_) xr[tid] = x[(t * B_ + (B_ - 1)) * I_ + tid];
  __syncthreads();
  float acc = b_ih[o] + b_hh[o];
  const float4* wp = (const float4*)(W_ih + o * I_);
#pragma unroll
  for (int j = 0; j < I_ / 4; ++j) {
    float4 w4 = wp[j];
    acc += w4.x * xr[4 * j] + w4.y * xr[4 * j + 1] + w4.z * xr[4 * j + 2] +
           w4.w * xr[4 * j + 3];
  }
  xh[t * H_ + o] = acc;
}

__global__ __launch_bounds__(256) void rnn_seq(
    const float* __restrict__ W_hh, float* __restrict__ xh,
    unsigned* hg) {
  const int tid = threadIdx.x;
  const int b = blockIdx.x;
  const int r = tid & 31;        // row within block's 32 rows
  const int seg = tid >> 5;      // 0..7 : 64-wide k-chunk
  const int row = b * R_ + r;
  const int k0 = seg * 64;
  const int wave = tid >> 6;
  const int own_lo = b * R_;

  __shared__ __align__(16) float h_l[H_];
  __shared__ __align__(16) float part[R_ * 4];  // transposed: [row][wave]

  // W_hh register-resident: thread (r,seg) holds W_hh[row][k0..k0+63].
  float w[64];
  {
    const float4* wp = (const float4*)(W_hh + row * H_ + k0);
#pragma unroll
    for (int j = 0; j < 16; ++j) {
      float4 v = wp[j];
      w[4 * j] = v.x; w[4 * j + 1] = v.y;
      w[4 * j + 2] = v.z; w[4 * j + 3] = v.w;
    }
  }
  for (int n = tid; n < H_; n += 256) h_l[n] = 0.0f;  // h_{-1} = 0

  // xi for step 0, prefetched; later steps prefetched during poll phase.
  float xiv = (tid < R_) ? xh[own_lo + tid] : 0.0f;
  wg_barrier_lds();

  // poll pair: words 2*tid, 2*tid+1 (u64). Own pairs skip (LDS-direct).
  const bool ownp = (tid >= b * (R_ / 2)) && (tid < (b + 1) * (R_ / 2));
  const unsigned long long sm = 0x8000000080000000ull;
  int D = 0;  // adaptive pre-poll delay, in s_sleep(1) (~64cy) units

  for (int s = 0; s < S_; ++s) {
    // partial dot, 4 independent accumulator chains
    float a0 = 0.f, a1 = 0.f, a2 = 0.f, a3 = 0.f;
    const float4* hp = (const float4*)(h_l + k0);
#pragma unroll
    for (int j = 0; j < 16; ++j) {
      float4 hv = hp[j];
      a0 = fmaf(w[4 * j + 0], hv.x, a0);
      a1 = fmaf(w[4 * j + 1], hv.y, a1);
      a2 = fmaf(w[4 * j + 2], hv.z, a2);
      a3 = fmaf(w[4 * j + 3], hv.w, a3);
    }
    float acc = (a0 + a1) + (a2 + a3);
    acc += __shfl_xor(acc, 32, 64);                 // fold seg pairs in-wave
    if ((tid & 32) == 0) part[r * 4 + wave] = acc;  // transposed for b128
    wg_barrier_lds();  // barrier A: partials visible

    const unsigned phase = (unsigned)((s >> 1) & 1);
    unsigned* buf = hg + (s & 1) * H_;

    if (tid < R_) {
      float4 p4 = *(const float4*)(part + tid * 4);  // ds_read_b128
      float sum = p4.x + p4.y + p4.z + p4.w + xiv;
      float h = fmaxf(sum, 0.0f);
      // exchange store FIRST: get it into the fabric ASAP.
      __hip_atomic_store(&buf[own_lo + tid],
                         __float_as_uint(h) | (phase << 31),
                         __ATOMIC_RELAXED, __HIP_MEMORY_SCOPE_AGENT);
      h_l[own_lo + tid] = h;            // own rows: LDS-direct, no RTT
      xh[s * H_ + own_lo + tid] = h;    // hseq (over consumed xi rows)
    }

    if (s == S_ - 1) break;  // no poll needed after last step

    // prefetch next step's xi (in flight across the barrier; used >RTT later)
    if (tid < R_) xiv = xh[(s + 1) * H_ + own_lo + tid];

    if (!ownp) {
      // phase-aligned first sample: wave sleeps max(D) of its active lanes --
      // exactly right, since the wave waits on its slowest pair anyway.
      for (int d = 0; d < D; ++d) __builtin_amdgcn_s_sleep(1);
      const unsigned long long ph64 = phase ? sm : 0ull;
      const unsigned long long* ap = (const unsigned long long*)buf + tid;
      unsigned long long v;
      int n = 0;
      do {
        v = __hip_atomic_load(ap, __ATOMIC_RELAXED, __HIP_MEMORY_SCOPE_AGENT);
        ++n;
      } while (((v ^ ph64) & sm) != 0ull);
      float2 hv;
      hv.x = __uint_as_float((unsigned)v & 0x7fffffffu);
      hv.y = __uint_as_float((unsigned)(v >> 32) & 0x7fffffffu);
      *(float2*)(h_l + 2 * tid) = hv;
      // adapt: sampled too early -> push later; on time -> creep earlier.
      if (n > 1) {
        D += (n - 1);
        if (D > 40) D = 40;
      } else if ((s & 7) == 0 && D > 0) {
        --D;
      }
    }
    wg_barrier_lds();  // barrier B: h_l complete
  }
}

__global__ __launch_bounds__(256) void rnn_post(
    const float* __restrict__ hseq, const float* __restrict__ W2,
    const float* __restrict__ b2, float* __restrict__ y) {
  const int t = blockIdx.x;
  const int tid = threadIdx.x;
  __shared__ float hl[H_];
  __shared__ float part[256];
  for (int n = tid; n < H_; n += 256) hl[n] = hseq[t * H_ + n];
  __syncthreads();
  const int o = tid >> 3;
  const int seg = tid & 7;
  float acc = 0.0f;
  if (o < O_) {
    const float4* wp = (const float4*)(W2 + o * H_ + seg * 64);
    const float4* hp = (const float4*)(hl + seg * 64);
#pragma unroll
    for (int j = 0; j < 16; ++j) {
      float4 w4 = wp[j];
      float4 h4 = hp[j];
      acc += w4.x * h4.x + w4.y * h4.y + w4.z * h4.z + w4.w * h4.w;
    }
  }
  part[tid] = acc;
  __syncthreads();
  if (tid < O_) {
    float sum = 0.0f;
#pragma unroll
    for (int j = 0; j < 8; ++j) sum += part[tid * 8 + j];
    y[t * O_ + tid] = sum + b2[tid];
  }
}

extern "C" void kernel_launch(void* const* d_in, const int* in_sizes, int n_in,
                              void* d_out, int out_size, void* d_ws, size_t ws_size,
                              hipStream_t stream) {
  const float* x    = (const float*)d_in[0];
  const float* W_ih = (const float*)d_in[1];
  const float* W_hh = (const float*)d_in[2];
  const float* b_ih = (const float*)d_in[3];
  const float* b_hh = (const float*)d_in[4];
  const float* W2   = (const float*)d_in[5];
  const float* b2   = (const float*)d_in[6];
  float* y = (float*)d_out;

  float* xh = (float*)d_ws;                  // [512*512] xi -> hseq (aliased)
  unsigned* hg = (unsigned*)(xh + S_ * H_);  // [2*512] sign-tagged exchange

  rnn_pre<<<dim3(S_, 2), 256, 0, stream>>>(x, W_ih, b_ih, b_hh, xh, hg);
  rnn_seq<<<G_, 256, 0, stream>>>(W_hh, xh, hg);
  rnn_post<<<S_, 256, 0, stream>>>(xh, W2, b2, y);
}